// Round 12
// baseline (1456.422 us; speedup 1.0000x reference)
//
#include <hip/hip_runtime.h>
#include <hip/hip_bf16.h>
#include <math.h>

#define N_NODES 50000
#define N_EDGES 800000
#define EMB 128
#define LH 256
#define NSENT 2048
#define MAXLEN 32
#define SCAN_NB 196   // ceil(50000/256)

typedef __attribute__((ext_vector_type(8))) short short8;
typedef __attribute__((ext_vector_type(4))) float f32x4;

__device__ __forceinline__ unsigned short f2bf_u(float f) {
    __hip_bfloat16 h = __float2bfloat16(f);
    return *reinterpret_cast<unsigned short*>(&h);
}
__device__ __forceinline__ float bfu2f(unsigned short u) {
    unsigned int x = ((unsigned int)u) << 16;
    return __uint_as_float(x);
}

// ---------------- CSR build ----------------

__global__ void k_hist(const int* __restrict__ dst, int* __restrict__ cnt) {
    int i = blockIdx.x * 256 + threadIdx.x;
    if (i < N_EDGES) atomicAdd(&cnt[dst[i]], 1);
}

__global__ void k_scan_blk(const int* __restrict__ cnt, int* __restrict__ row_ptr,
                           int* __restrict__ blk) {
    int b = blockIdx.x, t = threadIdx.x;
    int i = b * 256 + t;
    int lane = t & 63, wid = t >> 6;
    int v = (i < N_NODES) ? cnt[i] : 0;
    int x = v;
    #pragma unroll
    for (int off = 1; off < 64; off <<= 1) {
        int y = __shfl_up(x, off);
        if (lane >= off) x += y;
    }
    __shared__ int ws[4];
    if (lane == 63) ws[wid] = x;
    __syncthreads();
    if (t == 0) {
        int s = 0;
        #pragma unroll
        for (int j = 0; j < 4; j++) { int tmp = ws[j]; ws[j] = s; s += tmp; }
        blk[b] = s;
    }
    __syncthreads();
    if (i < N_NODES) row_ptr[i] = ws[wid] + x - v;
}

__global__ void k_scan_tot(int* __restrict__ blk) {
    int t = threadIdx.x;
    int lane = t & 63, wid = t >> 6;
    int v = (t < SCAN_NB) ? blk[t] : 0;
    int x = v;
    #pragma unroll
    for (int off = 1; off < 64; off <<= 1) {
        int y = __shfl_up(x, off);
        if (lane >= off) x += y;
    }
    __shared__ int ws[4];
    if (lane == 63) ws[wid] = x;
    __syncthreads();
    if (t == 0) {
        int s = 0;
        #pragma unroll
        for (int j = 0; j < 4; j++) { int tmp = ws[j]; ws[j] = s; s += tmp; }
    }
    __syncthreads();
    if (t < SCAN_NB) blk[t] = ws[wid] + x - v;
}

__global__ void k_scan_add(int* __restrict__ row_ptr, const int* __restrict__ blk) {
    int i = blockIdx.x * 256 + threadIdx.x;
    if (i < N_NODES) row_ptr[i] += blk[i >> 8];
    if (i == 0) row_ptr[N_NODES] = N_EDGES;
}

__global__ void k_scatter(const int* __restrict__ src, const int* __restrict__ dst,
                          const int* __restrict__ row_ptr, int* __restrict__ cnt,
                          int* __restrict__ edge_src) {
    int i = blockIdx.x * 256 + threadIdx.x;
    if (i < N_EDGES) {
        int d = dst[i];
        int pos = row_ptr[d] + atomicAdd(&cnt[d], 1);
        edge_src[pos] = src[i];
    }
}

// ---------------- fp32 -> bf16 convert (inputs) ----------------

__global__ void k_tobf16(const float* __restrict__ x, unsigned short* __restrict__ y) {
    int i = blockIdx.x * 256 + threadIdx.x;
    float4 v = ((const float4*)x)[i];
    ushort4 u;
    u.x = f2bf_u(v.x); u.y = f2bf_u(v.y); u.z = f2bf_u(v.z); u.w = f2bf_u(v.w);
    ((ushort4*)y)[i] = u;
}

// ---------------- aggregation: wave per node, 4 edge-slots x 16B/lane ----------------

__global__ void k_aggregate_bf(const unsigned short* __restrict__ feat,
                               const int* __restrict__ row_ptr,
                               const int* __restrict__ edge_src,
                               unsigned short* __restrict__ outb) {
    int w = (blockIdx.x * 256 + threadIdx.x) >> 6;
    int lane = threadIdx.x & 63;
    if (w >= N_NODES) return;
    int slot = lane >> 4, li = lane & 15;
    int beg = row_ptr[w], end = row_ptr[w + 1];
    float acc[8] = {};
    #pragma unroll 1
    for (int e = beg; e < end; e += 4) {
        int eidx = e + slot;
        if (eidx < end) {
            int s = edge_src[eidx];
            short8 v = *(const short8*)((const short*)feat + (size_t)s * EMB + li * 8);
            #pragma unroll
            for (int j = 0; j < 8; j++) acc[j] += bfu2f((unsigned short)v[j]);
        }
    }
    #pragma unroll
    for (int j = 0; j < 8; j++) {
        float t = acc[j];
        t += __shfl_xor(t, 16);
        t += __shfl_xor(t, 32);
        acc[j] = t;
    }
    if (slot == 0) {
        short8 o;
        #pragma unroll
        for (int j = 0; j < 8; j++) o[j] = (short)f2bf_u(acc[j]);
        *(short8*)((short*)outb + (size_t)w * EMB + li * 8) = o;
    }
}

// ---------------- GCN linear via MFMA ----------------

__global__ void __launch_bounds__(256)
k_gcn_mfma(const unsigned short* __restrict__ Ab,   // [M][128] bf16
           const unsigned short* __restrict__ Wb,   // [128][128] bf16
           const float* __restrict__ bias,
           unsigned short* __restrict__ outb,
           int M, int do_tanh) {
    int tid = threadIdx.x;
    int w = tid >> 6, lane = tid & 63;
    int l16 = lane & 15, quad = lane >> 4;
    int rbase = blockIdx.x * 64 + w * 16;
    int arow = rbase + l16;
    if (arow >= M) arow = M - 1;
    const short* Ap = (const short*)Ab + (size_t)arow * 128 + quad * 8;
    const short* Wp = (const short*)Wb;
    f32x4 acc[8] = {};
    #pragma unroll
    for (int ks = 0; ks < 4; ks++) {
        short8 a = *(const short8*)(Ap + ks * 32);
        #pragma unroll
        for (int ct = 0; ct < 8; ct++) {
            short8 b = *(const short8*)(Wp + (size_t)(ct * 16 + l16) * 128 + ks * 32 + quad * 8);
            acc[ct] = __builtin_amdgcn_mfma_f32_16x16x32_bf16(a, b, acc[ct], 0, 0, 0);
        }
    }
    #pragma unroll
    for (int ct = 0; ct < 8; ct++) {
        float bcol = bias[ct * 16 + l16];
        #pragma unroll
        for (int r = 0; r < 4; r++) {
            int row = rbase + quad * 4 + r;
            if (row < M) {
                float v = acc[ct][r] + bcol;
                if (do_tanh) v = tanhf(v);
                outb[(size_t)row * 128 + ct * 16 + l16] = f2bf_u(v);
            }
        }
    }
}

// ---------------- prep: Wpk (fragment-linear packed LSTM weights), bsum, W1b, W2b ----------------
// Wpk: fragment (ct,ks) at ((ct*12+ks)<<9) shorts; element lane*8+jj =
//   W[ct*16 + (lane&15)][ks*32 + (lane>>4)*8 + jj]  -> 1KB coalesced per wave-load.

__global__ void k_prep(const float* __restrict__ Wi, const float* __restrict__ Wh,
                       const float* __restrict__ bi, const float* __restrict__ bh,
                       const float* __restrict__ W1, const float* __restrict__ W2,
                       unsigned short* __restrict__ Wpk, float* __restrict__ bsum,
                       unsigned short* __restrict__ W1b, unsigned short* __restrict__ W2b) {
    int idx = blockIdx.x * 256 + threadIdx.x;
    if (idx < 1024 * 384) {
        int R = idx / 384, k = idx - R * 384;
        float v = (k < 128) ? Wi[R * 128 + k] : Wh[R * 256 + (k - 128)];
        int ct = R >> 4, cin = R & 15;
        int ks = k >> 5, kk = k & 31;
        int q = kk >> 3, jj = kk & 7;
        Wpk[((ct * 12 + ks) << 9) + (q * 16 + cin) * 8 + jj] = f2bf_u(v);
    } else if (idx < 1024 * 384 + 1024) {
        int r = idx - 1024 * 384;
        bsum[r] = bi[r] + bh[r];
    } else if (idx < 1024 * 384 + 1024 + 16384) {
        int r = idx - (1024 * 384 + 1024);
        W1b[r] = f2bf_u(W1[r]);
    } else if (idx < 1024 * 384 + 1024 + 32768) {
        int r = idx - (1024 * 384 + 1024 + 16384);
        W2b[r] = f2bf_u(W2[r]);
    }
}

// ---------------- LSTM: 64 self-contained blocks x 256 threads (4 waves) ----------------
// R4-R11 law: the compiler's VGPR target follows the occupancy heuristic (512thr->128,
// 1024thr->64) and scratch-spills anything beyond -> explicit staging vars always spilled.
// Fix: raise the BUDGET. 256-thread block + launch_bounds(256,1) = 1 wave/EU -> up to
// 512 VGPRs/wave (m97's regime, where the compiler itself hoists global loads across
// MFMAs with fine-grained vmcnt). Structure stays R9's proven-clean inline load->use;
// wave owns 64 units (16 ct = g*16 + w*4 + us). Live state ~290 VGPR (acc 128 + c 32 +
// bs 16 + transients) — fits even a 256-cap fallback. Weights stream from XCD L2:
// 768 KB/step/CU / ~64 B/cyc ≈ 5.3 us/step floor. h in LDS double-buffer, XOR-swizzled;
// c in registers; t=0 reads zeroed hsh.

__global__ void __launch_bounds__(256, 1)
k_lstm_block(const unsigned short* __restrict__ hn_bf,   // [N_NODES][128] bf16
             const unsigned short* __restrict__ Wpk,     // packed, see k_prep
             const float* __restrict__ bsum,             // [1024]
             const int* __restrict__ sidx,               // [NSENT][MAXLEN]
             const int* __restrict__ lengths,            // [NSENT]
             float* __restrict__ h_last) {               // [NSENT][256] fp32
    __shared__ unsigned short hsh[2][32 * 256];          // 32 KB
    __shared__ int nid_sh[32 * 33];                      // [m][t], pitch 33
    __shared__ int len_sh[32];
    int tid = threadIdx.x;
    int w = tid >> 6, lane = tid & 63;                   // w in [0,4)
    int l16 = lane & 15, quad = lane >> 4;
    int s0 = blockIdx.x * 32;

    for (int i = tid; i < 32 * 32; i += 256)
        nid_sh[(i >> 5) * 33 + (i & 31)] = sidx[(size_t)(s0 + (i >> 5)) * MAXLEN + (i & 31)];
    if (tid < 32) len_sh[tid] = lengths[s0 + tid];
    for (int i = tid; i < 32 * 256; i += 256) hsh[0][i] = 0;   // h_{-1} = 0
    __syncthreads();

    const short* hnp = (const short*)hn_bf;
    const short* Wp = (const short*)Wpk;

    float bs[4][4];   // [g][us]
    #pragma unroll
    for (int g = 0; g < 4; g++)
        #pragma unroll
        for (int us = 0; us < 4; us++)
            bs[g][us] = bsum[g * 256 + w * 64 + us * 16 + l16];

    float c_reg[2][4][4] = {};   // [mt][us][r]
    int swz = (l16 & 7) * 8;     // XOR term (shorts) for h LDS chunk swizzle

    #pragma unroll 1
    for (int t = 0; t < MAXLEN; t++) {
        const short* hin = (const short*)hsh[t & 1];
        unsigned short* hout = hsh[(t & 1) ^ 1];

        int nid0 = nid_sh[l16 * 33 + t];
        int nid1 = nid_sh[(16 + l16) * 33 + t];
        const short* Ax0 = hnp + (size_t)nid0 * 128 + quad * 8;
        const short* Ax1 = hnp + (size_t)nid1 * 128 + quad * 8;

        f32x4 acc0[16] = {};   // m-tile 0 (m = quad*4+r), index g*4+us
        f32x4 acc1[16] = {};   // m-tile 1 (m = 16+quad*4+r)

        // fully-unrolled step: 192 independent 1KB b-loads + 384 MFMAs exposed to the
        // scheduler; with the 512-VGPR budget the compiler hoists loads (m97 behavior)
        #pragma unroll
        for (int ks = 0; ks < 12; ks++) {
            short8 a0, a1;
            if (ks < 4) {
                a0 = *(const short8*)(Ax0 + ks * 32);
                a1 = *(const short8*)(Ax1 + ks * 32);
            } else {
                int go = ((ks - 4) * 4 + quad) * 8;
                a0 = *(const short8*)(hin + l16 * 256 + (go ^ swz));
                a1 = *(const short8*)(hin + (16 + l16) * 256 + (go ^ swz));
            }
            #pragma unroll
            for (int c16 = 0; c16 < 16; c16++) {
                int ct = (c16 >> 2) * 16 + w * 4 + (c16 & 3);
                short8 b = *(const short8*)(Wp + ((ct * 12 + ks) << 9) + lane * 8);
                acc0[c16] = __builtin_amdgcn_mfma_f32_16x16x32_bf16(a0, b, acc0[c16], 0, 0, 0);
                acc1[c16] = __builtin_amdgcn_mfma_f32_16x16x32_bf16(a1, b, acc1[c16], 0, 0, 0);
            }
        }

        // epilogue: per-lane pointwise update; c in registers; h -> LDS (swizzled)
        #pragma unroll
        for (int mt = 0; mt < 2; mt++)
            #pragma unroll
            for (int us = 0; us < 4; us++)
                #pragma unroll
                for (int r = 0; r < 4; r++) {
                    int m = mt * 16 + quad * 4 + r;
                    int u = w * 64 + us * 16 + l16;
                    float gi  = (mt ? acc1[0 * 4 + us][r] : acc0[0 * 4 + us][r]) + bs[0][us];
                    float gf  = (mt ? acc1[1 * 4 + us][r] : acc0[1 * 4 + us][r]) + bs[1][us];
                    float gg  = (mt ? acc1[2 * 4 + us][r] : acc0[2 * 4 + us][r]) + bs[2][us];
                    float go_ = (mt ? acc1[3 * 4 + us][r] : acc0[3 * 4 + us][r]) + bs[3][us];
                    float i_ = 1.f / (1.f + expf(-gi));
                    float f_ = 1.f / (1.f + expf(-gf));
                    float g_ = tanhf(gg);
                    float o_ = 1.f / (1.f + expf(-go_));
                    float c = f_ * c_reg[mt][us][r] + i_ * g_;
                    c_reg[mt][us][r] = c;
                    float h = o_ * tanhf(c);
                    hout[m * 256 + ((((u >> 3) ^ (m & 7)) << 3) | (u & 7))] = f2bf_u(h);
                    if (len_sh[m] - 1 == t) h_last[(size_t)(s0 + m) * 256 + u] = h;
                }
        __syncthreads();
    }
}

// ---------------- classifier ----------------

__global__ void k_classifier(const float* __restrict__ h_last,
                             const float* __restrict__ Wc1, const float* __restrict__ bc1,
                             const float* __restrict__ Wc2, const float* __restrict__ bc2,
                             float* __restrict__ out) {
    int lane = threadIdx.x & 63;
    int wslot = threadIdx.x >> 6;
    int s = blockIdx.x * 4 + wslot;
    __shared__ float e_sh[4][256];
    const float* hr = h_last + (size_t)s * 256;
    #pragma unroll
    for (int i = 0; i < 4; i++) {
        float v = hr[lane + 64 * i];
        e_sh[wslot][lane + 64 * i] = fmaxf(v, 0.f);
    }
    __syncthreads();
    float zpart = 0.f;
    #pragma unroll
    for (int jj = 0; jj < 2; jj++) {
        int j = lane + 64 * jj;
        float a = bc1[j];
        const float4* wr = (const float4*)(Wc1 + (size_t)j * 256);
        #pragma unroll 8
        for (int k4 = 0; k4 < 64; k4++) {
            float4 wv = wr[k4];
            float4 e = *(const float4*)&e_sh[wslot][k4 * 4];
            a += wv.x * e.x + wv.y * e.y + wv.z * e.z + wv.w * e.w;
        }
        a = fmaxf(a, 0.f);
        zpart += a * Wc2[j];
    }
    #pragma unroll
    for (int off = 32; off > 0; off >>= 1) zpart += __shfl_down(zpart, off);
    if (lane == 0) out[s] = zpart + bc2[0];
}

// ---------------- launcher ----------------

extern "C" void kernel_launch(void* const* d_in, const int* in_sizes, int n_in,
                              void* d_out, int out_size, void* d_ws, size_t ws_size,
                              hipStream_t stream) {
    const float* inputs = (const float*)d_in[0];
    const float* W1  = (const float*)d_in[1];
    const float* b1  = (const float*)d_in[2];
    const float* W2  = (const float*)d_in[3];
    const float* b2  = (const float*)d_in[4];
    const float* Wi  = (const float*)d_in[5];
    const float* Wh  = (const float*)d_in[6];
    const float* bi  = (const float*)d_in[7];
    const float* bh  = (const float*)d_in[8];
    const float* Wc1 = (const float*)d_in[9];
    const float* bc1 = (const float*)d_in[10];
    const float* Wc2 = (const float*)d_in[11];
    const float* bc2 = (const float*)d_in[12];
    const int* src      = (const int*)d_in[13];
    const int* dst      = (const int*)d_in[14];
    const int* sidx     = (const int*)d_in[15];
    const int* lengths  = (const int*)d_in[16];
    float* out = (float*)d_out;

    char* ws = (char*)d_ws;
    size_t off = 0;
    auto alloc = [&](size_t bytes) -> void* {
        void* p = ws + off;
        off = (off + bytes + 255) & ~(size_t)255;
        return p;
    };
    unsigned short* in_bf  = (unsigned short*)alloc(2 * (size_t)N_NODES * EMB);
    unsigned short* agg_bf = (unsigned short*)alloc(2 * (size_t)N_NODES * EMB);
    unsigned short* h_bf   = (unsigned short*)alloc(2 * (size_t)N_NODES * EMB);
    unsigned short* hn_bf  = (unsigned short*)alloc(2 * (size_t)N_NODES * EMB);
    int*   row_ptr  = (int*)alloc(sizeof(int) * (N_NODES + 1));
    int*   cnt      = (int*)alloc(sizeof(int) * N_NODES);
    int*   blk      = (int*)alloc(sizeof(int) * SCAN_NB);
    int*   edge_src = (int*)alloc(sizeof(int) * N_EDGES);
    unsigned short* Wpk  = (unsigned short*)alloc(2 * 1024 * 384);
    unsigned short* W1b  = (unsigned short*)alloc(2 * 128 * 128);
    unsigned short* W2b  = (unsigned short*)alloc(2 * 128 * 128);
    float* bsum     = (float*)alloc(sizeof(float) * 1024);
    float* hlast    = (float*)alloc(sizeof(float) * NSENT * LH);

    // weight prep (independent of everything else)
    k_prep<<<(1024 * 384 + 1024 + 32768 + 255) / 256, 256, 0, stream>>>(
        Wi, Wh, bi, bh, W1, W2, Wpk, bsum, W1b, W2b);

    // CSR build
    hipMemsetAsync(cnt, 0, sizeof(int) * N_NODES, stream);
    k_hist<<<(N_EDGES + 255) / 256, 256, 0, stream>>>(dst, cnt);
    k_scan_blk<<<SCAN_NB, 256, 0, stream>>>(cnt, row_ptr, blk);
    k_scan_tot<<<1, 256, 0, stream>>>(blk);
    k_scan_add<<<SCAN_NB, 256, 0, stream>>>(row_ptr, blk);
    hipMemsetAsync(cnt, 0, sizeof(int) * N_NODES, stream);
    k_scatter<<<(N_EDGES + 255) / 256, 256, 0, stream>>>(src, dst, row_ptr, cnt, edge_src);

    // GCN (bf16 path)
    k_tobf16<<<(N_NODES * EMB / 4 + 255) / 256, 256, 0, stream>>>(inputs, in_bf);
    k_aggregate_bf<<<(N_NODES * 64) / 256, 256, 0, stream>>>(in_bf, row_ptr, edge_src, agg_bf);
    k_gcn_mfma<<<(N_NODES + 63) / 64, 256, 0, stream>>>(agg_bf, W1b, b1, h_bf, N_NODES, 1);
    k_aggregate_bf<<<(N_NODES * 64) / 256, 256, 0, stream>>>(h_bf, row_ptr, edge_src, agg_bf);
    k_gcn_mfma<<<(N_NODES + 63) / 64, 256, 0, stream>>>(agg_bf, W2b, b2, hn_bf, N_NODES, 0);

    // LSTM: 64 self-contained blocks x 256 threads (1 wave/EU -> 512-VGPR budget)
    k_lstm_block<<<64, 256, 0, stream>>>(hn_bf, Wpk, bsum, sidx, lengths, hlast);

    // classifier
    k_classifier<<<NSENT / 4, 256, 0, stream>>>(hlast, Wc1, bc1, Wc2, bc2, out);
}

// Round 13
// 909.726 us; speedup vs baseline: 1.6009x; 1.6009x over previous
//
#include <hip/hip_runtime.h>
#include <hip/hip_bf16.h>
#include <math.h>

#define N_NODES 50000
#define N_EDGES 800000
#define EMB 128
#define LH 256
#define NSENT 2048
#define MAXLEN 32
#define SCAN_NB 196   // ceil(50000/256)

typedef __attribute__((ext_vector_type(8))) short short8;
typedef __attribute__((ext_vector_type(4))) float f32x4;

__device__ __forceinline__ unsigned short f2bf_u(float f) {
    __hip_bfloat16 h = __float2bfloat16(f);
    return *reinterpret_cast<unsigned short*>(&h);
}
__device__ __forceinline__ float bfu2f(unsigned short u) {
    unsigned int x = ((unsigned int)u) << 16;
    return __uint_as_float(x);
}

// async global->LDS, 16B/lane; gsrc per-lane, LDS dst = wave-uniform base + lane*16
__device__ __forceinline__ void gload_lds16(const void* gsrc, void* ldst) {
    __builtin_amdgcn_global_load_lds(
        (const __attribute__((address_space(1))) unsigned int*)gsrc,
        (__attribute__((address_space(3))) unsigned int*)ldst, 16, 0, 0);
}

// ---------------- CSR build ----------------

__global__ void k_hist(const int* __restrict__ dst, int* __restrict__ cnt) {
    int i = blockIdx.x * 256 + threadIdx.x;
    if (i < N_EDGES) atomicAdd(&cnt[dst[i]], 1);
}

__global__ void k_scan_blk(const int* __restrict__ cnt, int* __restrict__ row_ptr,
                           int* __restrict__ blk) {
    int b = blockIdx.x, t = threadIdx.x;
    int i = b * 256 + t;
    int lane = t & 63, wid = t >> 6;
    int v = (i < N_NODES) ? cnt[i] : 0;
    int x = v;
    #pragma unroll
    for (int off = 1; off < 64; off <<= 1) {
        int y = __shfl_up(x, off);
        if (lane >= off) x += y;
    }
    __shared__ int ws[4];
    if (lane == 63) ws[wid] = x;
    __syncthreads();
    if (t == 0) {
        int s = 0;
        #pragma unroll
        for (int j = 0; j < 4; j++) { int tmp = ws[j]; ws[j] = s; s += tmp; }
        blk[b] = s;
    }
    __syncthreads();
    if (i < N_NODES) row_ptr[i] = ws[wid] + x - v;
}

__global__ void k_scan_tot(int* __restrict__ blk) {
    int t = threadIdx.x;
    int lane = t & 63, wid = t >> 6;
    int v = (t < SCAN_NB) ? blk[t] : 0;
    int x = v;
    #pragma unroll
    for (int off = 1; off < 64; off <<= 1) {
        int y = __shfl_up(x, off);
        if (lane >= off) x += y;
    }
    __shared__ int ws[4];
    if (lane == 63) ws[wid] = x;
    __syncthreads();
    if (t == 0) {
        int s = 0;
        #pragma unroll
        for (int j = 0; j < 4; j++) { int tmp = ws[j]; ws[j] = s; s += tmp; }
    }
    __syncthreads();
    if (t < SCAN_NB) blk[t] = ws[wid] + x - v;
}

__global__ void k_scan_add(int* __restrict__ row_ptr, const int* __restrict__ blk) {
    int i = blockIdx.x * 256 + threadIdx.x;
    if (i < N_NODES) row_ptr[i] += blk[i >> 8];
    if (i == 0) row_ptr[N_NODES] = N_EDGES;
}

__global__ void k_scatter(const int* __restrict__ src, const int* __restrict__ dst,
                          const int* __restrict__ row_ptr, int* __restrict__ cnt,
                          int* __restrict__ edge_src) {
    int i = blockIdx.x * 256 + threadIdx.x;
    if (i < N_EDGES) {
        int d = dst[i];
        int pos = row_ptr[d] + atomicAdd(&cnt[d], 1);
        edge_src[pos] = src[i];
    }
}

// ---------------- fp32 -> bf16 convert (inputs) ----------------

__global__ void k_tobf16(const float* __restrict__ x, unsigned short* __restrict__ y) {
    int i = blockIdx.x * 256 + threadIdx.x;
    float4 v = ((const float4*)x)[i];
    ushort4 u;
    u.x = f2bf_u(v.x); u.y = f2bf_u(v.y); u.z = f2bf_u(v.z); u.w = f2bf_u(v.w);
    ((ushort4*)y)[i] = u;
}

// ---------------- aggregation: wave per node, 4 edge-slots x 16B/lane ----------------

__global__ void k_aggregate_bf(const unsigned short* __restrict__ feat,
                               const int* __restrict__ row_ptr,
                               const int* __restrict__ edge_src,
                               unsigned short* __restrict__ outb) {
    int w = (blockIdx.x * 256 + threadIdx.x) >> 6;
    int lane = threadIdx.x & 63;
    if (w >= N_NODES) return;
    int slot = lane >> 4, li = lane & 15;
    int beg = row_ptr[w], end = row_ptr[w + 1];
    float acc[8] = {};
    #pragma unroll 1
    for (int e = beg; e < end; e += 4) {
        int eidx = e + slot;
        if (eidx < end) {
            int s = edge_src[eidx];
            short8 v = *(const short8*)((const short*)feat + (size_t)s * EMB + li * 8);
            #pragma unroll
            for (int j = 0; j < 8; j++) acc[j] += bfu2f((unsigned short)v[j]);
        }
    }
    #pragma unroll
    for (int j = 0; j < 8; j++) {
        float t = acc[j];
        t += __shfl_xor(t, 16);
        t += __shfl_xor(t, 32);
        acc[j] = t;
    }
    if (slot == 0) {
        short8 o;
        #pragma unroll
        for (int j = 0; j < 8; j++) o[j] = (short)f2bf_u(acc[j]);
        *(short8*)((short*)outb + (size_t)w * EMB + li * 8) = o;
    }
}

// ---------------- GCN linear via MFMA ----------------

__global__ void __launch_bounds__(256)
k_gcn_mfma(const unsigned short* __restrict__ Ab,   // [M][128] bf16
           const unsigned short* __restrict__ Wb,   // [128][128] bf16
           const float* __restrict__ bias,
           unsigned short* __restrict__ outb,
           int M, int do_tanh) {
    int tid = threadIdx.x;
    int w = tid >> 6, lane = tid & 63;
    int l16 = lane & 15, quad = lane >> 4;
    int rbase = blockIdx.x * 64 + w * 16;
    int arow = rbase + l16;
    if (arow >= M) arow = M - 1;
    const short* Ap = (const short*)Ab + (size_t)arow * 128 + quad * 8;
    const short* Wp = (const short*)Wb;
    f32x4 acc[8] = {};
    #pragma unroll
    for (int ks = 0; ks < 4; ks++) {
        short8 a = *(const short8*)(Ap + ks * 32);
        #pragma unroll
        for (int ct = 0; ct < 8; ct++) {
            short8 b = *(const short8*)(Wp + (size_t)(ct * 16 + l16) * 128 + ks * 32 + quad * 8);
            acc[ct] = __builtin_amdgcn_mfma_f32_16x16x32_bf16(a, b, acc[ct], 0, 0, 0);
        }
    }
    #pragma unroll
    for (int ct = 0; ct < 8; ct++) {
        float bcol = bias[ct * 16 + l16];
        #pragma unroll
        for (int r = 0; r < 4; r++) {
            int row = rbase + quad * 4 + r;
            if (row < M) {
                float v = acc[ct][r] + bcol;
                if (do_tanh) v = tanhf(v);
                outb[(size_t)row * 128 + ct * 16 + l16] = f2bf_u(v);
            }
        }
    }
}

// ---------------- prep: Wpk (fragment-linear packed LSTM weights), bsum, W1b, W2b ----------------
// Wpk: fragment (ct,ks) at ((ct*12+ks)<<9) shorts; element lane*8+jj =
//   W[ct*16 + (lane&15)][ks*32 + (lane>>4)*8 + jj]  -> 1KB coalesced per wave-load.

__global__ void k_prep(const float* __restrict__ Wi, const float* __restrict__ Wh,
                       const float* __restrict__ bi, const float* __restrict__ bh,
                       const float* __restrict__ W1, const float* __restrict__ W2,
                       unsigned short* __restrict__ Wpk, float* __restrict__ bsum,
                       unsigned short* __restrict__ W1b, unsigned short* __restrict__ W2b) {
    int idx = blockIdx.x * 256 + threadIdx.x;
    if (idx < 1024 * 384) {
        int R = idx / 384, k = idx - R * 384;
        float v = (k < 128) ? Wi[R * 128 + k] : Wh[R * 256 + (k - 128)];
        int ct = R >> 4, cin = R & 15;
        int ks = k >> 5, kk = k & 31;
        int q = kk >> 3, jj = kk & 7;
        Wpk[((ct * 12 + ks) << 9) + (q * 16 + cin) * 8 + jj] = f2bf_u(v);
    } else if (idx < 1024 * 384 + 1024) {
        int r = idx - 1024 * 384;
        bsum[r] = bi[r] + bh[r];
    } else if (idx < 1024 * 384 + 1024 + 16384) {
        int r = idx - (1024 * 384 + 1024);
        W1b[r] = f2bf_u(W1[r]);
    } else if (idx < 1024 * 384 + 1024 + 32768) {
        int r = idx - (1024 * 384 + 1024 + 16384);
        W2b[r] = f2bf_u(W2[r]);
    }
}

// ---------------- LSTM: 64 blocks x 512 threads; weights via async global_load_lds ----------------
// R5-R12 law: register-staged weight pipelines always spill (compiler scratch-demotes any
// staging beyond its heuristic VGPR target). Fix: stage through LDS with async
// global_load_lds (zero VGPR cost, cannot spill; m97-verified high-BW path).
// Per ks: issue next-ks staging (8x1KB per wave) into the alternate 64KB buffer, compute
// 16 MFMAs with B from LDS (contiguous ds_read_b128 = conflict-free), barrier (drains
// vmcnt -> staging(ks+1) overlapped compute(ks)).  x_t staged via gather global_load_lds
// (issued at ks=4: WAR-safe after ks=3 barrier, ready at next step's ks=0).
// Single h buffer is barrier-race-free: h reads (ks>=4) precede the ks=11 barrier;
// epilogue writes follow it; next step's reads are 4+ barriers later.
// Register profile = R4's proven-clean shape (~100 VGPR at (512,2)).

__global__ void __launch_bounds__(512, 2)
k_lstm_block(const unsigned short* __restrict__ hn_bf,   // [N_NODES][128] bf16
             const unsigned short* __restrict__ Wpk,     // packed, see k_prep
             const float* __restrict__ bsum,             // [1024]
             const int* __restrict__ sidx,               // [NSENT][MAXLEN]
             const int* __restrict__ lengths,            // [NSENT]
             float* __restrict__ h_last) {               // [NSENT][256] fp32
    __shared__ unsigned short wbuf[2 * 32768];           // 2 x 64 KB weight staging
    __shared__ unsigned short xbuf[32 * 128];            // 8 KB x_t (chunk-swizzled)
    __shared__ unsigned short hsh[32 * 256];             // 16 KB h (single buffer, swizzled)
    __shared__ int nid_sh[32 * 33];                      // [m][t], pitch 33
    __shared__ int len_sh[32];
    int tid = threadIdx.x;
    int w = tid >> 6, lane = tid & 63;                   // w in [0,8)
    int l16 = lane & 15, quad = lane >> 4;
    int s0 = blockIdx.x * 32;

    for (int i = tid; i < 32 * 32; i += 512)
        nid_sh[(i >> 5) * 33 + (i & 31)] = sidx[(size_t)(s0 + (i >> 5)) * MAXLEN + (i & 31)];
    if (tid < 32) len_sh[tid] = lengths[s0 + tid];
    for (int i = tid; i < 32 * 256; i += 512) hsh[i] = 0;   // h_{-1} = 0
    __syncthreads();                                     // nid_sh ready for x staging

    const short* hnp = (const short*)hn_bf;
    const short* Wp = (const short*)Wpk;

    // preamble: stage ks=0 fragments -> wbuf[0]; stage x_0 -> xbuf
    #pragma unroll
    for (int j = 0; j < 8; j++) {
        int ct = w * 8 + j;
        gload_lds16(Wp + ((ct * 12 + 0) << 9) + lane * 8, (void*)(wbuf + ct * 512));
    }
    {
        int m = w * 4 + (lane >> 4);
        int nid = nid_sh[m * 33 + 0];
        gload_lds16(hnp + (size_t)nid * 128 + (((lane & 15) ^ (m & 7)) * 8),
                    (void*)(xbuf + w * 512));
    }
    __syncthreads();                                     // drain preamble staging

    float bs[4][2];
    #pragma unroll
    for (int g = 0; g < 4; g++)
        #pragma unroll
        for (int us = 0; us < 2; us++)
            bs[g][us] = bsum[g * 256 + w * 32 + us * 16 + l16];

    float c_reg[2][2][4] = {};   // [mt][us][r]
    int swz = (l16 & 7) * 8;     // XOR term (shorts) for h LDS chunk swizzle

    #pragma unroll 1
    for (int t = 0; t < MAXLEN; t++) {
        f32x4 acc0[8] = {};   // m-tile 0 (m = quad*4+r), index g*2+us
        f32x4 acc1[8] = {};   // m-tile 1 (m = 16+quad*4+r)

        #pragma unroll 1
        for (int ks = 0; ks < 12; ks++) {
            // (1) async-stage next ks's fragments into the alternate buffer
            int ksn = (ks == 11) ? 0 : ks + 1;
            unsigned short* dstb = wbuf + (((ks + 1) & 1) << 15);
            #pragma unroll
            for (int j = 0; j < 8; j++) {
                int ct = w * 8 + j;
                gload_lds16(Wp + ((ct * 12 + ksn) << 9) + lane * 8, (void*)(dstb + ct * 512));
            }
            // (1b) stage x_{t+1} at ks=4 (x reads done at ks=3 barrier; ready next step)
            if (ks == 4 && t + 1 < MAXLEN) {
                int m = w * 4 + (lane >> 4);
                int nid = nid_sh[m * 33 + (t + 1)];
                gload_lds16(hnp + (size_t)nid * 128 + (((lane & 15) ^ (m & 7)) * 8),
                            (void*)(xbuf + w * 512));
            }
            // (2) A operands from LDS
            short8 a0, a1;
            if (ks < 4) {
                int c = ((ks * 4 + quad) ^ (l16 & 7)) * 8;   // (16+l16)&7 == l16&7
                a0 = *(const short8*)((const short*)xbuf + l16 * 128 + c);
                a1 = *(const short8*)((const short*)xbuf + (16 + l16) * 128 + c);
            } else {
                int go = ((ks - 4) * 4 + quad) * 8;
                a0 = *(const short8*)((const short*)hsh + l16 * 256 + (go ^ swz));
                a1 = *(const short8*)((const short*)hsh + (16 + l16) * 256 + (go ^ swz));
            }
            // (3) B from current LDS buffer + MFMA
            const short* bcur = (const short*)wbuf + ((ks & 1) << 15);
            #pragma unroll
            for (int c8 = 0; c8 < 8; c8++) {
                int ct = (c8 >> 1) * 16 + w * 2 + (c8 & 1);
                short8 b = *(const short8*)(bcur + ct * 512 + lane * 8);
                acc0[c8] = __builtin_amdgcn_mfma_f32_16x16x32_bf16(a0, b, acc0[c8], 0, 0, 0);
                acc1[c8] = __builtin_amdgcn_mfma_f32_16x16x32_bf16(a1, b, acc1[c8], 0, 0, 0);
            }
            // (4) barrier: drains staging (overlapped with (2)-(3)), orders LDS reuse
            __syncthreads();
        }

        // epilogue: per-lane pointwise update; c in registers; h -> LDS (swizzled)
        #pragma unroll
        for (int mt = 0; mt < 2; mt++)
            #pragma unroll
            for (int us = 0; us < 2; us++)
                #pragma unroll
                for (int r = 0; r < 4; r++) {
                    int m = mt * 16 + quad * 4 + r;
                    int u = w * 32 + us * 16 + l16;
                    float gi  = (mt ? acc1[0 * 2 + us][r] : acc0[0 * 2 + us][r]) + bs[0][us];
                    float gf  = (mt ? acc1[1 * 2 + us][r] : acc0[1 * 2 + us][r]) + bs[1][us];
                    float gg  = (mt ? acc1[2 * 2 + us][r] : acc0[2 * 2 + us][r]) + bs[2][us];
                    float go_ = (mt ? acc1[3 * 2 + us][r] : acc0[3 * 2 + us][r]) + bs[3][us];
                    float i_ = 1.f / (1.f + expf(-gi));
                    float f_ = 1.f / (1.f + expf(-gf));
                    float g_ = tanhf(gg);
                    float o_ = 1.f / (1.f + expf(-go_));
                    float c = f_ * c_reg[mt][us][r] + i_ * g_;
                    c_reg[mt][us][r] = c;
                    float h = o_ * tanhf(c);
                    hsh[m * 256 + ((((u >> 3) ^ (m & 7)) << 3) | (u & 7))] = f2bf_u(h);
                    if (len_sh[m] - 1 == t) h_last[(size_t)(s0 + m) * 256 + u] = h;
                }
        // no barrier needed: next h read (ks=4, t+1) is 5 barriers downstream
    }
}

// ---------------- classifier ----------------

__global__ void k_classifier(const float* __restrict__ h_last,
                             const float* __restrict__ Wc1, const float* __restrict__ bc1,
                             const float* __restrict__ Wc2, const float* __restrict__ bc2,
                             float* __restrict__ out) {
    int lane = threadIdx.x & 63;
    int wslot = threadIdx.x >> 6;
    int s = blockIdx.x * 4 + wslot;
    __shared__ float e_sh[4][256];
    const float* hr = h_last + (size_t)s * 256;
    #pragma unroll
    for (int i = 0; i < 4; i++) {
        float v = hr[lane + 64 * i];
        e_sh[wslot][lane + 64 * i] = fmaxf(v, 0.f);
    }
    __syncthreads();
    float zpart = 0.f;
    #pragma unroll
    for (int jj = 0; jj < 2; jj++) {
        int j = lane + 64 * jj;
        float a = bc1[j];
        const float4* wr = (const float4*)(Wc1 + (size_t)j * 256);
        #pragma unroll 8
        for (int k4 = 0; k4 < 64; k4++) {
            float4 wv = wr[k4];
            float4 e = *(const float4*)&e_sh[wslot][k4 * 4];
            a += wv.x * e.x + wv.y * e.y + wv.z * e.z + wv.w * e.w;
        }
        a = fmaxf(a, 0.f);
        zpart += a * Wc2[j];
    }
    #pragma unroll
    for (int off = 32; off > 0; off >>= 1) zpart += __shfl_down(zpart, off);
    if (lane == 0) out[s] = zpart + bc2[0];
}

// ---------------- launcher ----------------

extern "C" void kernel_launch(void* const* d_in, const int* in_sizes, int n_in,
                              void* d_out, int out_size, void* d_ws, size_t ws_size,
                              hipStream_t stream) {
    const float* inputs = (const float*)d_in[0];
    const float* W1  = (const float*)d_in[1];
    const float* b1  = (const float*)d_in[2];
    const float* W2  = (const float*)d_in[3];
    const float* b2  = (const float*)d_in[4];
    const float* Wi  = (const float*)d_in[5];
    const float* Wh  = (const float*)d_in[6];
    const float* bi  = (const float*)d_in[7];
    const float* bh  = (const float*)d_in[8];
    const float* Wc1 = (const float*)d_in[9];
    const float* bc1 = (const float*)d_in[10];
    const float* Wc2 = (const float*)d_in[11];
    const float* bc2 = (const float*)d_in[12];
    const int* src      = (const int*)d_in[13];
    const int* dst      = (const int*)d_in[14];
    const int* sidx     = (const int*)d_in[15];
    const int* lengths  = (const int*)d_in[16];
    float* out = (float*)d_out;

    char* ws = (char*)d_ws;
    size_t off = 0;
    auto alloc = [&](size_t bytes) -> void* {
        void* p = ws + off;
        off = (off + bytes + 255) & ~(size_t)255;
        return p;
    };
    unsigned short* in_bf  = (unsigned short*)alloc(2 * (size_t)N_NODES * EMB);
    unsigned short* agg_bf = (unsigned short*)alloc(2 * (size_t)N_NODES * EMB);
    unsigned short* h_bf   = (unsigned short*)alloc(2 * (size_t)N_NODES * EMB);
    unsigned short* hn_bf  = (unsigned short*)alloc(2 * (size_t)N_NODES * EMB);
    int*   row_ptr  = (int*)alloc(sizeof(int) * (N_NODES + 1));
    int*   cnt      = (int*)alloc(sizeof(int) * N_NODES);
    int*   blk      = (int*)alloc(sizeof(int) * SCAN_NB);
    int*   edge_src = (int*)alloc(sizeof(int) * N_EDGES);
    unsigned short* Wpk  = (unsigned short*)alloc(2 * 1024 * 384);
    unsigned short* W1b  = (unsigned short*)alloc(2 * 128 * 128);
    unsigned short* W2b  = (unsigned short*)alloc(2 * 128 * 128);
    float* bsum     = (float*)alloc(sizeof(float) * 1024);
    float* hlast    = (float*)alloc(sizeof(float) * NSENT * LH);

    // weight prep (independent of everything else)
    k_prep<<<(1024 * 384 + 1024 + 32768 + 255) / 256, 256, 0, stream>>>(
        Wi, Wh, bi, bh, W1, W2, Wpk, bsum, W1b, W2b);

    // CSR build
    hipMemsetAsync(cnt, 0, sizeof(int) * N_NODES, stream);
    k_hist<<<(N_EDGES + 255) / 256, 256, 0, stream>>>(dst, cnt);
    k_scan_blk<<<SCAN_NB, 256, 0, stream>>>(cnt, row_ptr, blk);
    k_scan_tot<<<1, 256, 0, stream>>>(blk);
    k_scan_add<<<SCAN_NB, 256, 0, stream>>>(row_ptr, blk);
    hipMemsetAsync(cnt, 0, sizeof(int) * N_NODES, stream);
    k_scatter<<<(N_EDGES + 255) / 256, 256, 0, stream>>>(src, dst, row_ptr, cnt, edge_src);

    // GCN (bf16 path)
    k_tobf16<<<(N_NODES * EMB / 4 + 255) / 256, 256, 0, stream>>>(inputs, in_bf);
    k_aggregate_bf<<<(N_NODES * 64) / 256, 256, 0, stream>>>(in_bf, row_ptr, edge_src, agg_bf);
    k_gcn_mfma<<<(N_NODES + 63) / 64, 256, 0, stream>>>(agg_bf, W1b, b1, h_bf, N_NODES, 1);
    k_aggregate_bf<<<(N_NODES * 64) / 256, 256, 0, stream>>>(h_bf, row_ptr, edge_src, agg_bf);
    k_gcn_mfma<<<(N_NODES + 63) / 64, 256, 0, stream>>>(agg_bf, W2b, b2, hn_bf, N_NODES, 0);

    // LSTM: 64 blocks x 512 threads; weights stream via async global_load_lds
    k_lstm_block<<<64, 512, 0, stream>>>(hn_bf, Wpk, bsum, sidx, lengths, hlast);

    // classifier
    k_classifier<<<NSENT / 4, 256, 0, stream>>>(hlast, Wc1, bc1, Wc2, bc2, out);
}

// Round 14
// 827.104 us; speedup vs baseline: 1.7609x; 1.0999x over previous
//
#include <hip/hip_runtime.h>
#include <hip/hip_bf16.h>
#include <math.h>

#define N_NODES 50000
#define N_EDGES 800000
#define EMB 128
#define LH 256
#define NSENT 2048
#define MAXLEN 32
#define SCAN_NB 196   // ceil(50000/256)

typedef __attribute__((ext_vector_type(8))) short short8;
typedef __attribute__((ext_vector_type(4))) float f32x4;

// s_waitcnt immediates (gfx9 encoding: vmcnt [3:0]+[15:14], expcnt [6:4], lgkmcnt [11:8])
#define WAITVM8()   __builtin_amdgcn_s_waitcnt(0xF78)   // vmcnt(8), exp/lgkm unconstrained
#define WAITVM0()   __builtin_amdgcn_s_waitcnt(0xF70)   // vmcnt(0)
#define WAITLGKM0() __builtin_amdgcn_s_waitcnt(0xC07F)  // lgkmcnt(0), vm/exp unconstrained

__device__ __forceinline__ unsigned short f2bf_u(float f) {
    __hip_bfloat16 h = __float2bfloat16(f);
    return *reinterpret_cast<unsigned short*>(&h);
}
__device__ __forceinline__ float bfu2f(unsigned short u) {
    unsigned int x = ((unsigned int)u) << 16;
    return __uint_as_float(x);
}

// async global->LDS, 16B/lane; gsrc per-lane, LDS dst = wave-uniform base + lane*16
__device__ __forceinline__ void gload_lds16(const void* gsrc, void* ldst) {
    __builtin_amdgcn_global_load_lds(
        (const __attribute__((address_space(1))) unsigned int*)gsrc,
        (__attribute__((address_space(3))) unsigned int*)ldst, 16, 0, 0);
}

// ---------------- CSR build ----------------

__global__ void k_hist(const int* __restrict__ dst, int* __restrict__ cnt) {
    int i = blockIdx.x * 256 + threadIdx.x;
    if (i < N_EDGES) atomicAdd(&cnt[dst[i]], 1);
}

__global__ void k_scan_blk(const int* __restrict__ cnt, int* __restrict__ row_ptr,
                           int* __restrict__ blk) {
    int b = blockIdx.x, t = threadIdx.x;
    int i = b * 256 + t;
    int lane = t & 63, wid = t >> 6;
    int v = (i < N_NODES) ? cnt[i] : 0;
    int x = v;
    #pragma unroll
    for (int off = 1; off < 64; off <<= 1) {
        int y = __shfl_up(x, off);
        if (lane >= off) x += y;
    }
    __shared__ int ws[4];
    if (lane == 63) ws[wid] = x;
    __syncthreads();
    if (t == 0) {
        int s = 0;
        #pragma unroll
        for (int j = 0; j < 4; j++) { int tmp = ws[j]; ws[j] = s; s += tmp; }
        blk[b] = s;
    }
    __syncthreads();
    if (i < N_NODES) row_ptr[i] = ws[wid] + x - v;
}

__global__ void k_scan_tot(int* __restrict__ blk) {
    int t = threadIdx.x;
    int lane = t & 63, wid = t >> 6;
    int v = (t < SCAN_NB) ? blk[t] : 0;
    int x = v;
    #pragma unroll
    for (int off = 1; off < 64; off <<= 1) {
        int y = __shfl_up(x, off);
        if (lane >= off) x += y;
    }
    __shared__ int ws[4];
    if (lane == 63) ws[wid] = x;
    __syncthreads();
    if (t == 0) {
        int s = 0;
        #pragma unroll
        for (int j = 0; j < 4; j++) { int tmp = ws[j]; ws[j] = s; s += tmp; }
    }
    __syncthreads();
    if (t < SCAN_NB) blk[t] = ws[wid] + x - v;
}

__global__ void k_scan_add(int* __restrict__ row_ptr, const int* __restrict__ blk) {
    int i = blockIdx.x * 256 + threadIdx.x;
    if (i < N_NODES) row_ptr[i] += blk[i >> 8];
    if (i == 0) row_ptr[N_NODES] = N_EDGES;
}

__global__ void k_scatter(const int* __restrict__ src, const int* __restrict__ dst,
                          const int* __restrict__ row_ptr, int* __restrict__ cnt,
                          int* __restrict__ edge_src) {
    int i = blockIdx.x * 256 + threadIdx.x;
    if (i < N_EDGES) {
        int d = dst[i];
        int pos = row_ptr[d] + atomicAdd(&cnt[d], 1);
        edge_src[pos] = src[i];
    }
}

// ---------------- fp32 -> bf16 convert (inputs) ----------------

__global__ void k_tobf16(const float* __restrict__ x, unsigned short* __restrict__ y) {
    int i = blockIdx.x * 256 + threadIdx.x;
    float4 v = ((const float4*)x)[i];
    ushort4 u;
    u.x = f2bf_u(v.x); u.y = f2bf_u(v.y); u.z = f2bf_u(v.z); u.w = f2bf_u(v.w);
    ((ushort4*)y)[i] = u;
}

// ---------------- aggregation: wave per node, 4 edge-slots x 16B/lane ----------------

__global__ void k_aggregate_bf(const unsigned short* __restrict__ feat,
                               const int* __restrict__ row_ptr,
                               const int* __restrict__ edge_src,
                               unsigned short* __restrict__ outb) {
    int w = (blockIdx.x * 256 + threadIdx.x) >> 6;
    int lane = threadIdx.x & 63;
    if (w >= N_NODES) return;
    int slot = lane >> 4, li = lane & 15;
    int beg = row_ptr[w], end = row_ptr[w + 1];
    float acc[8] = {};
    #pragma unroll 1
    for (int e = beg; e < end; e += 4) {
        int eidx = e + slot;
        if (eidx < end) {
            int s = edge_src[eidx];
            short8 v = *(const short8*)((const short*)feat + (size_t)s * EMB + li * 8);
            #pragma unroll
            for (int j = 0; j < 8; j++) acc[j] += bfu2f((unsigned short)v[j]);
        }
    }
    #pragma unroll
    for (int j = 0; j < 8; j++) {
        float t = acc[j];
        t += __shfl_xor(t, 16);
        t += __shfl_xor(t, 32);
        acc[j] = t;
    }
    if (slot == 0) {
        short8 o;
        #pragma unroll
        for (int j = 0; j < 8; j++) o[j] = (short)f2bf_u(acc[j]);
        *(short8*)((short*)outb + (size_t)w * EMB + li * 8) = o;
    }
}

// ---------------- GCN linear via MFMA ----------------

__global__ void __launch_bounds__(256)
k_gcn_mfma(const unsigned short* __restrict__ Ab,   // [M][128] bf16
           const unsigned short* __restrict__ Wb,   // [128][128] bf16
           const float* __restrict__ bias,
           unsigned short* __restrict__ outb,
           int M, int do_tanh) {
    int tid = threadIdx.x;
    int w = tid >> 6, lane = tid & 63;
    int l16 = lane & 15, quad = lane >> 4;
    int rbase = blockIdx.x * 64 + w * 16;
    int arow = rbase + l16;
    if (arow >= M) arow = M - 1;
    const short* Ap = (const short*)Ab + (size_t)arow * 128 + quad * 8;
    const short* Wp = (const short*)Wb;
    f32x4 acc[8] = {};
    #pragma unroll
    for (int ks = 0; ks < 4; ks++) {
        short8 a = *(const short8*)(Ap + ks * 32);
        #pragma unroll
        for (int ct = 0; ct < 8; ct++) {
            short8 b = *(const short8*)(Wp + (size_t)(ct * 16 + l16) * 128 + ks * 32 + quad * 8);
            acc[ct] = __builtin_amdgcn_mfma_f32_16x16x32_bf16(a, b, acc[ct], 0, 0, 0);
        }
    }
    #pragma unroll
    for (int ct = 0; ct < 8; ct++) {
        float bcol = bias[ct * 16 + l16];
        #pragma unroll
        for (int r = 0; r < 4; r++) {
            int row = rbase + quad * 4 + r;
            if (row < M) {
                float v = acc[ct][r] + bcol;
                if (do_tanh) v = tanhf(v);
                outb[(size_t)row * 128 + ct * 16 + l16] = f2bf_u(v);
            }
        }
    }
}

// ---------------- prep: Wpk (fragment-linear packed LSTM weights), bsum, W1b, W2b ----------------
// Wpk: fragment (ct,ks) at ((ct*12+ks)<<9) shorts; element lane*8+jj =
//   W[ct*16 + (lane&15)][ks*32 + (lane>>4)*8 + jj]  -> 1KB coalesced per wave-load.

__global__ void k_prep(const float* __restrict__ Wi, const float* __restrict__ Wh,
                       const float* __restrict__ bi, const float* __restrict__ bh,
                       const float* __restrict__ W1, const float* __restrict__ W2,
                       unsigned short* __restrict__ Wpk, float* __restrict__ bsum,
                       unsigned short* __restrict__ W1b, unsigned short* __restrict__ W2b) {
    int idx = blockIdx.x * 256 + threadIdx.x;
    if (idx < 1024 * 384) {
        int R = idx / 384, k = idx - R * 384;
        float v = (k < 128) ? Wi[R * 128 + k] : Wh[R * 256 + (k - 128)];
        int ct = R >> 4, cin = R & 15;
        int ks = k >> 5, kk = k & 31;
        int q = kk >> 3, jj = kk & 7;
        Wpk[((ct * 12 + ks) << 9) + (q * 16 + cin) * 8 + jj] = f2bf_u(v);
    } else if (idx < 1024 * 384 + 1024) {
        int r = idx - 1024 * 384;
        bsum[r] = bi[r] + bh[r];
    } else if (idx < 1024 * 384 + 1024 + 16384) {
        int r = idx - (1024 * 384 + 1024);
        W1b[r] = f2bf_u(W1[r]);
    } else if (idx < 1024 * 384 + 1024 + 32768) {
        int r = idx - (1024 * 384 + 1024 + 16384);
        W2b[r] = f2bf_u(W2[r]);
    }
}

// ---------------- LSTM: 64 blocks x 512 threads; WAVE-PRIVATE async weight staging ----------------
// R13 post-mortem: per-ks __syncthreads drains vmcnt(0) -> staging never overlaps compute
// (3.7k cyc/ks vs ~1.1k floor). Fix: each wave stages exactly the 8 fragments IT consumes
// into its own 2x8KB LDS slice -> weight sync is per-wave s_waitcnt vmcnt(8) (wait the
// older stage, leave the prefetch in flight; m135-verified semantics), NO barrier in the
// ks loop. WAR on buffer reuse fenced by lgkmcnt(0) + sched_barrier before re-staging.
// One __syncthreads per step (h/x cross-wave). Register profile = R13's clean 96 VGPR.

__global__ void __launch_bounds__(512, 2)
k_lstm_block(const unsigned short* __restrict__ hn_bf,   // [N_NODES][128] bf16
             const unsigned short* __restrict__ Wpk,     // packed, see k_prep
             const float* __restrict__ bsum,             // [1024]
             const int* __restrict__ sidx,               // [NSENT][MAXLEN]
             const int* __restrict__ lengths,            // [NSENT]
             float* __restrict__ h_last) {               // [NSENT][256] fp32
    __shared__ unsigned short wbuf[2][8][8][512];        // [parity][wave][c8][512] = 128 KB
    __shared__ unsigned short xbuf[32 * 128];            // 8 KB x_t (chunk-swizzled)
    __shared__ unsigned short hsh[32 * 256];             // 16 KB h (single buffer, swizzled)
    __shared__ int nid_sh[32 * 33];                      // [m][t], pitch 33
    __shared__ int len_sh[32];
    int tid = threadIdx.x;
    int w = tid >> 6, lane = tid & 63;                   // w in [0,8)
    int l16 = lane & 15, quad = lane >> 4;
    int s0 = blockIdx.x * 32;

    for (int i = tid; i < 32 * 32; i += 512)
        nid_sh[(i >> 5) * 33 + (i & 31)] = sidx[(size_t)(s0 + (i >> 5)) * MAXLEN + (i & 31)];
    if (tid < 32) len_sh[tid] = lengths[s0 + tid];
    for (int i = tid; i < 32 * 256; i += 512) hsh[i] = 0;   // h_{-1} = 0
    __syncthreads();                                     // nid_sh ready for x staging

    const short* hnp = (const short*)hn_bf;
    const short* Wp = (const short*)Wpk;

    // wave-private weight stage: fragments this wave consumes (ct = g*16 + w*2 + us)
    auto stage_w = [&](int parity, int ks) {
        #pragma unroll
        for (int c8 = 0; c8 < 8; c8++) {
            int ct = (c8 >> 1) * 16 + w * 2 + (c8 & 1);
            gload_lds16(Wp + ((ct * 12 + ks) << 9) + lane * 8, (void*)&wbuf[parity][w][c8][0]);
        }
    };
    // cooperative x gather for step tt (4 rows per wave, chunk-swizzled)
    auto stage_x = [&](int tt) {
        int m = w * 4 + (lane >> 4);
        int nid = nid_sh[m * 33 + tt];
        gload_lds16(hnp + (size_t)nid * 128 + (((lane & 15) ^ (m & 7)) * 8),
                    (void*)(xbuf + w * 512));
    };

    stage_x(0);   // x_0 in flight; completes before first use via vmcnt(8) at ks=0

    float bs[4][2];
    #pragma unroll
    for (int g = 0; g < 4; g++)
        #pragma unroll
        for (int us = 0; us < 2; us++)
            bs[g][us] = bsum[g * 256 + w * 32 + us * 16 + l16];

    float c_reg[2][2][4] = {};   // [mt][us][r]
    int swz = (l16 & 7) * 8;     // XOR term (shorts) for h LDS chunk swizzle

    #pragma unroll 1
    for (int t = 0; t < MAXLEN; t++) {
        stage_w(0, 0);           // ks0 -> buf0
        stage_w(1, 1);           // ks1 -> buf1 (prefetch)

        f32x4 acc0[8] = {};      // m-tile 0 (m = quad*4+r), index g*2+us
        f32x4 acc1[8] = {};      // m-tile 1 (m = 16+quad*4+r)

        #pragma unroll 1
        for (int ks = 0; ks < 12; ks++) {
            // wait: all but the newest 8 staging loads complete -> stage(ks) landed
            if (ks == 11) WAITVM0(); else WAITVM8();

            short8 a0, a1;
            if (ks < 4) {
                int c = ((ks * 4 + quad) ^ (l16 & 7)) * 8;   // (16+l16)&7 == l16&7
                a0 = *(const short8*)((const short*)xbuf + l16 * 128 + c);
                a1 = *(const short8*)((const short*)xbuf + (16 + l16) * 128 + c);
            } else {
                int go = ((ks - 4) * 4 + quad) * 8;
                a0 = *(const short8*)((const short*)hsh + l16 * 256 + (go ^ swz));
                a1 = *(const short8*)((const short*)hsh + (16 + l16) * 256 + (go ^ swz));
            }
            const short* bb = (const short*)&wbuf[ks & 1][w][0][0];
            #pragma unroll
            for (int c8 = 0; c8 < 8; c8++) {
                short8 b = *(const short8*)(bb + c8 * 512 + lane * 8);
                acc0[c8] = __builtin_amdgcn_mfma_f32_16x16x32_bf16(a0, b, acc0[c8], 0, 0, 0);
                acc1[c8] = __builtin_amdgcn_mfma_f32_16x16x32_bf16(a1, b, acc1[c8], 0, 0, 0);
            }
            if (ks < 10) {
                WAITLGKM0();     // ds_reads of this buffer complete (WAR fence)
#if __has_builtin(__builtin_amdgcn_sched_barrier)
                __builtin_amdgcn_sched_barrier(0);
#endif
                stage_w(ks & 1, ks + 2);   // overwrite just-consumed buffer
            }
        }

        // epilogue: per-lane pointwise update; c in registers; h -> LDS (swizzled)
        #pragma unroll
        for (int mt = 0; mt < 2; mt++)
            #pragma unroll
            for (int us = 0; us < 2; us++)
                #pragma unroll
                for (int r = 0; r < 4; r++) {
                    int m = mt * 16 + quad * 4 + r;
                    int u = w * 32 + us * 16 + l16;
                    float gi  = (mt ? acc1[0 * 2 + us][r] : acc0[0 * 2 + us][r]) + bs[0][us];
                    float gf  = (mt ? acc1[1 * 2 + us][r] : acc0[1 * 2 + us][r]) + bs[1][us];
                    float gg  = (mt ? acc1[2 * 2 + us][r] : acc0[2 * 2 + us][r]) + bs[2][us];
                    float go_ = (mt ? acc1[3 * 2 + us][r] : acc0[3 * 2 + us][r]) + bs[3][us];
                    float i_ = 1.f / (1.f + expf(-gi));
                    float f_ = 1.f / (1.f + expf(-gf));
                    float g_ = tanhf(gg);
                    float o_ = 1.f / (1.f + expf(-go_));
                    float c = f_ * c_reg[mt][us][r] + i_ * g_;
                    c_reg[mt][us][r] = c;
                    float h = o_ * tanhf(c);
                    hsh[m * 256 + ((((u >> 3) ^ (m & 7)) << 3) | (u & 7))] = f2bf_u(h);
                    if (len_sh[m] - 1 == t) h_last[(size_t)(s0 + m) * 256 + u] = h;
                }

        // stage x_{t+1} (xbuf reads finished at ks=3), then the ONE per-step barrier:
        // orders h/x across waves; drains the lone x-gather load (cheap).
        if (t + 1 < MAXLEN) stage_x(t + 1);
        __syncthreads();
    }
}

// ---------------- classifier ----------------

__global__ void k_classifier(const float* __restrict__ h_last,
                             const float* __restrict__ Wc1, const float* __restrict__ bc1,
                             const float* __restrict__ Wc2, const float* __restrict__ bc2,
                             float* __restrict__ out) {
    int lane = threadIdx.x & 63;
    int wslot = threadIdx.x >> 6;
    int s = blockIdx.x * 4 + wslot;
    __shared__ float e_sh[4][256];
    const float* hr = h_last + (size_t)s * 256;
    #pragma unroll
    for (int i = 0; i < 4; i++) {
        float v = hr[lane + 64 * i];
        e_sh[wslot][lane + 64 * i] = fmaxf(v, 0.f);
    }
    __syncthreads();
    float zpart = 0.f;
    #pragma unroll
    for (int jj = 0; jj < 2; jj++) {
        int j = lane + 64 * jj;
        float a = bc1[j];
        const float4* wr = (const float4*)(Wc1 + (size_t)j * 256);
        #pragma unroll 8
        for (int k4 = 0; k4 < 64; k4++) {
            float4 wv = wr[k4];
            float4 e = *(const float4*)&e_sh[wslot][k4 * 4];
            a += wv.x * e.x + wv.y * e.y + wv.z * e.z + wv.w * e.w;
        }
        a = fmaxf(a, 0.f);
        zpart += a * Wc2[j];
    }
    #pragma unroll
    for (int off = 32; off > 0; off >>= 1) zpart += __shfl_down(zpart, off);
    if (lane == 0) out[s] = zpart + bc2[0];
}

// ---------------- launcher ----------------

extern "C" void kernel_launch(void* const* d_in, const int* in_sizes, int n_in,
                              void* d_out, int out_size, void* d_ws, size_t ws_size,
                              hipStream_t stream) {
    const float* inputs = (const float*)d_in[0];
    const float* W1  = (const float*)d_in[1];
    const float* b1  = (const float*)d_in[2];
    const float* W2  = (const float*)d_in[3];
    const float* b2  = (const float*)d_in[4];
    const float* Wi  = (const float*)d_in[5];
    const float* Wh  = (const float*)d_in[6];
    const float* bi  = (const float*)d_in[7];
    const float* bh  = (const float*)d_in[8];
    const float* Wc1 = (const float*)d_in[9];
    const float* bc1 = (const float*)d_in[10];
    const float* Wc2 = (const float*)d_in[11];
    const float* bc2 = (const float*)d_in[12];
    const int* src      = (const int*)d_in[13];
    const int* dst      = (const int*)d_in[14];
    const int* sidx     = (const int*)d_in[15];
    const int* lengths  = (const int*)d_in[16];
    float* out = (float*)d_out;

    char* ws = (char*)d_ws;
    size_t off = 0;
    auto alloc = [&](size_t bytes) -> void* {
        void* p = ws + off;
        off = (off + bytes + 255) & ~(size_t)255;
        return p;
    };
    unsigned short* in_bf  = (unsigned short*)alloc(2 * (size_t)N_NODES * EMB);
    unsigned short* agg_bf = (unsigned short*)alloc(2 * (size_t)N_NODES * EMB);
    unsigned short* h_bf   = (unsigned short*)alloc(2 * (size_t)N_NODES * EMB);
    unsigned short* hn_bf  = (unsigned short*)alloc(2 * (size_t)N_NODES * EMB);
    int*   row_ptr  = (int*)alloc(sizeof(int) * (N_NODES + 1));
    int*   cnt      = (int*)alloc(sizeof(int) * N_NODES);
    int*   blk      = (int*)alloc(sizeof(int) * SCAN_NB);
    int*   edge_src = (int*)alloc(sizeof(int) * N_EDGES);
    unsigned short* Wpk  = (unsigned short*)alloc(2 * 1024 * 384);
    unsigned short* W1b  = (unsigned short*)alloc(2 * 128 * 128);
    unsigned short* W2b  = (unsigned short*)alloc(2 * 128 * 128);
    float* bsum     = (float*)alloc(sizeof(float) * 1024);
    float* hlast    = (float*)alloc(sizeof(float) * NSENT * LH);

    // weight prep (independent of everything else)
    k_prep<<<(1024 * 384 + 1024 + 32768 + 255) / 256, 256, 0, stream>>>(
        Wi, Wh, bi, bh, W1, W2, Wpk, bsum, W1b, W2b);

    // CSR build
    hipMemsetAsync(cnt, 0, sizeof(int) * N_NODES, stream);
    k_hist<<<(N_EDGES + 255) / 256, 256, 0, stream>>>(dst, cnt);
    k_scan_blk<<<SCAN_NB, 256, 0, stream>>>(cnt, row_ptr, blk);
    k_scan_tot<<<1, 256, 0, stream>>>(blk);
    k_scan_add<<<SCAN_NB, 256, 0, stream>>>(row_ptr, blk);
    hipMemsetAsync(cnt, 0, sizeof(int) * N_NODES, stream);
    k_scatter<<<(N_EDGES + 255) / 256, 256, 0, stream>>>(src, dst, row_ptr, cnt, edge_src);

    // GCN (bf16 path)
    k_tobf16<<<(N_NODES * EMB / 4 + 255) / 256, 256, 0, stream>>>(inputs, in_bf);
    k_aggregate_bf<<<(N_NODES * 64) / 256, 256, 0, stream>>>(in_bf, row_ptr, edge_src, agg_bf);
    k_gcn_mfma<<<(N_NODES + 63) / 64, 256, 0, stream>>>(agg_bf, W1b, b1, h_bf, N_NODES, 1);
    k_aggregate_bf<<<(N_NODES * 64) / 256, 256, 0, stream>>>(h_bf, row_ptr, edge_src, agg_bf);
    k_gcn_mfma<<<(N_NODES + 63) / 64, 256, 0, stream>>>(agg_bf, W2b, b2, hn_bf, N_NODES, 0);

    // LSTM: 64 blocks x 512 threads; wave-private async weight staging, 1 barrier/step
    k_lstm_block<<<64, 512, 0, stream>>>(hn_bf, Wpk, bsum, sidx, lengths, hlast);

    // classifier
    k_classifier<<<NSENT / 4, 256, 0, stream>>>(hlast, Wc1, bc1, Wc2, bc2, out);
}